// Round 8
// baseline (467.147 us; speedup 1.0000x reference)
//
#include <hip/hip_runtime.h>
#include <hip/hip_bf16.h>

// Attention with softmax over the QUERY axis (axis=1):
//   attn[:,q,k] = exp(S[q,k]) / Z[k],  Z[k] = sum_q exp(S[q,k])
//   out = expS @ (diag(1/Z) V)   -- rZ folded into V by k_scalev.
// B=2, N=8192, D=256.
// R8: k_attn rewritten with the swapped-QK trick: S^T = mfma(K,Q) puts each
// lane's P row exactly in mfma_16x16x16 A-fragment layout -> P stays in
// registers, no P-LDS, ONE barrier per k-tile (was 2 + lgkm drain).
// Per wave: 32q x 32k-half; PV over full 256d; k-halves merged at epilogue.

#define N_ 8192
#define SCALE 0.0625f

typedef __attribute__((ext_vector_type(8))) short short8;
typedef __attribute__((ext_vector_type(4))) short short4_t;
typedef __attribute__((ext_vector_type(4))) float f32x4;
typedef __attribute__((ext_vector_type(4))) unsigned short ushort4_t;

__device__ inline unsigned short f2bf(float f) {
    unsigned int x = __float_as_uint(f);
    unsigned int r = (x + 0x7fffu + ((x >> 16) & 1u)) >> 16;  // RNE
    return (unsigned short)r;
}

__device__ inline short8 ldg8(const unsigned short* p) {
    return *reinterpret_cast<const short8*>(p);
}

__device__ inline short8 cvt8(const float* p) {
    float4 a = *(const float4*)p;
    float4 b = *(const float4*)(p + 4);
    short8 r;
    r[0] = (short)f2bf(a.x); r[1] = (short)f2bf(a.y);
    r[2] = (short)f2bf(a.z); r[3] = (short)f2bf(a.w);
    r[4] = (short)f2bf(b.x); r[5] = (short)f2bf(b.y);
    r[6] = (short)f2bf(b.z); r[7] = (short)f2bf(b.w);
    return r;
}

__device__ inline f32x4 mfma16(short8 a, short8 b, f32x4 c) {
    return __builtin_amdgcn_mfma_f32_16x16x32_bf16(a, b, c, 0, 0, 0);
}

#if defined(__has_builtin) && __has_builtin(__builtin_amdgcn_mfma_f32_16x16x16bf16_1k)
__device__ inline f32x4 mfma1616(short4_t a, short4_t b, f32x4 c) {
    return __builtin_amdgcn_mfma_f32_16x16x16bf16_1k(a, b, c, 0, 0, 0);
}
#else
__device__ inline f32x4 mfma1616(short4_t a, short4_t b, f32x4 c) {
    asm("v_mfma_f32_16x16x16_bf16 %0, %1, %2, %0" : "+v"(c) : "v"(a), "v"(b));
    return c;
}
#endif

__device__ inline float bf2f(unsigned short u) {
    return __uint_as_float(((unsigned)u) << 16);
}

#define PIN8(v) asm volatile("" : "+v"(v))

typedef __attribute__((address_space(3))) unsigned int lds_u32;
typedef __attribute__((address_space(1))) const unsigned int glb_u32;
__device__ __forceinline__ void gll16(const void* g, void* l) {
    __builtin_amdgcn_global_load_lds((glb_u32*)g, (lds_u32*)l, 16, 0, 0);
}
#define WAIT_VM0()   asm volatile("s_waitcnt vmcnt(0)" ::: "memory")
#define BARRIER()    __builtin_amdgcn_s_barrier()

// ---------------------------------------------------------------------------
// Kernel 0: W (3 x 256x256 f32) -> Wb (768x256 bf16), concatenated Q|K|V.
// ---------------------------------------------------------------------------
__global__ __launch_bounds__(256) void k_cvtw(
    const float* __restrict__ Wq, const float* __restrict__ Wk,
    const float* __restrict__ Wv, unsigned short* __restrict__ Wb)
{
    int t = blockIdx.x * 256 + threadIdx.x;
    int e8 = t * 8;
    const float* src = (e8 < 65536) ? Wq + e8
                     : (e8 < 131072) ? Wk + (e8 - 65536)
                                     : Wv + (e8 - 131072);
    *reinterpret_cast<short8*>(Wb + e8) = cvt8(src);
}

// ---------------------------------------------------------------------------
// Kernel 1: QKV projection, x read ONCE (proven R5).
// ---------------------------------------------------------------------------
__global__ __launch_bounds__(512) void k_proj(
    const float* __restrict__ x, const unsigned short* __restrict__ Wb,
    unsigned short* __restrict__ Qb, unsigned short* __restrict__ Kb,
    unsigned short* __restrict__ Vt)
{
    __shared__ unsigned short sX[64 * 256];   // 32 KB, XOR-swizzled
    int rb = blockIdx.x;
    int tid = threadIdx.x, w = tid >> 6, lane = tid & 63;
    int lr = lane & 15, lg = lane >> 4;

#pragma unroll
    for (int i = 0; i < 4; ++i) {
        int g = tid + i * 512;
        int r = g >> 5, c = g & 31;
        int off = (r * 512 + c * 16) ^ ((r & 7) << 4);
        *reinterpret_cast<short8*>(reinterpret_cast<char*>(sX) + off) =
            cvt8(x + (size_t)(rb * 64 + r) * 256 + c * 8);
    }
    __syncthreads();

    f32x4 acc[4][6] = {};
#pragma unroll
    for (int ks = 0; ks < 8; ++ks) {
        int coff = (ks * 32 + lg * 8) * 2;
        short8 xf[4];
#pragma unroll
        for (int rf = 0; rf < 4; ++rf) {
            int row = rf * 16 + lr;
            int off = (row * 512 + coff) ^ ((row & 7) << 4);
            xf[rf] = *reinterpret_cast<const short8*>(
                reinterpret_cast<const char*>(sX) + off);
        }
#pragma unroll
        for (int cf = 0; cf < 6; ++cf) {
            int e = w * 96 + cf * 16 + lr;
            short8 bfr = ldg8(Wb + (size_t)e * 256 + ks * 32 + lg * 8);
#pragma unroll
            for (int rf = 0; rf < 4; ++rf)
                acc[rf][cf] = mfma16(xf[rf], bfr, acc[rf][cf]);
        }
    }

#pragma unroll
    for (int rf = 0; rf < 4; ++rf)
#pragma unroll
        for (int cf = 0; cf < 6; ++cf) {
            int e0c = w * 96 + cf * 16;
            int mat = e0c >> 8;               // 0:Q 1:K 2:V
            int ecol = (e0c & 255) + lr;
            int rbase = rb * 64 + rf * 16 + lg * 4;
            if (mat < 2) {
                unsigned short* dst = (mat == 0) ? Qb : Kb;
#pragma unroll
                for (int r = 0; r < 4; ++r)
                    dst[(size_t)(rbase + r) * 256 + ecol] = f2bf(acc[rf][cf][r]);
            } else {
                int bidx = rbase >> 13, nr = rbase & 8191;
                ushort4_t v;
#pragma unroll
                for (int r = 0; r < 4; ++r) v[r] = f2bf(acc[rf][cf][r]);
                *reinterpret_cast<ushort4_t*>(
                    Vt + ((size_t)bidx * 256 + ecol) * 8192 + nr) = v;
            }
        }
}

// ---------------------------------------------------------------------------
// Kernel 2: Z partials (R7 version: pinned K frags, waves_per_eu(2,2)).
// ---------------------------------------------------------------------------
__global__
__attribute__((amdgpu_flat_work_group_size(512, 512), amdgpu_waves_per_eu(2, 2)))
void k_zsum(
    const unsigned short* __restrict__ Qb, const unsigned short* __restrict__ Kb,
    float* __restrict__ Zpart)
{
    __shared__ unsigned short sK[64 * 256];
    __shared__ float zred[8][64];
    int qc = blockIdx.x, kt = blockIdx.y, b = blockIdx.z;
    int tid = threadIdx.x;

    for (int i = 0; i < 4; ++i) {
        int g = tid + i * 512;
        int r = g >> 5, c = g & 31;
        int off = (r * 512 + c * 16) ^ ((r & 7) << 4);
        *reinterpret_cast<short8*>(reinterpret_cast<char*>(sK) + off) =
            ldg8(Kb + (size_t)(b * N_ + kt * 64 + r) * 256 + c * 8);
    }
    __syncthreads();

    int w = tid >> 6, lane = tid & 63, lr = lane & 15, lg = lane >> 4;

    short8 kfr[4][8];
#pragma unroll
    for (int n = 0; n < 4; ++n)
#pragma unroll
        for (int ks = 0; ks < 8; ++ks) {
            int krow = n * 16 + lr;
            int off = (krow * 512 + (ks * 32 + lg * 8) * 2) ^ ((krow & 7) << 4);
            kfr[n][ks] = *reinterpret_cast<const short8*>(
                reinterpret_cast<const char*>(sK) + off);
            PIN8(kfr[n][ks]);
        }

    float zsum[4] = {0.f, 0.f, 0.f, 0.f};
    for (int it = 0; it < 32; ++it) {
        int qb = qc * 4096 + it * 128 + w * 16;
        const unsigned short* qrow = Qb + (size_t)(b * N_ + qb + lr) * 256;
        f32x4 acc[4] = {};
        for (int ks = 0; ks < 8; ++ks) {
            int d0 = ks * 32 + lg * 8;
            short8 a = ldg8(qrow + d0);
#pragma unroll
            for (int n = 0; n < 4; ++n)
                acc[n] = mfma16(a, kfr[n][ks], acc[n]);
        }
#pragma unroll
        for (int n = 0; n < 4; ++n)
#pragma unroll
            for (int r = 0; r < 4; ++r)
                zsum[n] += __expf(acc[n][r] * SCALE);
    }
#pragma unroll
    for (int n = 0; n < 4; ++n) {
        float v = zsum[n];
        v += __shfl_xor(v, 16);
        v += __shfl_xor(v, 32);
        if (lg == 0) zred[w][n * 16 + lr] = v;
    }
    __syncthreads();
    if (tid < 64) {
        float s = 0.f;
        for (int ww = 0; ww < 8; ++ww) s += zred[ww][tid];
        Zpart[(size_t)(qc * 2 + b) * N_ + kt * 64 + tid] = s;
    }
}

// ---------------------------------------------------------------------------
// Kernel 2.5: V' = V / Z (in place on Vt, bf16). Reads Zpart directly
// (k_rz folded in).
// ---------------------------------------------------------------------------
__global__ __launch_bounds__(256) void k_scalev(
    unsigned short* __restrict__ Vt, const float* __restrict__ Zpart)
{
    int t = blockIdx.x * 256 + threadIdx.x;
    int b = t >> 18, g = t & 262143;
    int d = g >> 10, k8 = (g & 1023) * 8;
    unsigned short* p = Vt + ((size_t)b * 256 + d) * 8192 + k8;
    short8 v = *reinterpret_cast<short8*>(p);
    const float* za = Zpart + (size_t)b * N_ + k8;          // qc=0
    const float* zb = Zpart + (size_t)(2 + b) * N_ + k8;    // qc=1
    float4 a0 = *(const float4*)za, a1 = *(const float4*)(za + 4);
    float4 b0 = *(const float4*)zb, b1 = *(const float4*)(zb + 4);
    float rv[8] = {1.f/(a0.x+b0.x), 1.f/(a0.y+b0.y), 1.f/(a0.z+b0.z), 1.f/(a0.w+b0.w),
                   1.f/(a1.x+b1.x), 1.f/(a1.y+b1.y), 1.f/(a1.z+b1.z), 1.f/(a1.w+b1.w)};
    short8 o;
#pragma unroll
    for (int j = 0; j < 8; ++j)
        o[j] = (short)f2bf(bf2f((unsigned short)v[j]) * rv[j]);
    *reinterpret_cast<short8*>(p) = o;
}

// ---------------------------------------------------------------------------
// Kernel 3 (v8): out[q,d] = sum_k exp(S[q,k]*SCALE) * V'[k,d].
// Grid (64 qt, NKH, 2 b), 512 thr (8 waves). qtile=128, k-tile 64 per kt.
// Waves: wqs=w&3 (4 strips of 32q), wkh=w>>2 (2 k-halves of 32k).
// Per wave: S^T = mfma(K,Q) 32 MFMAs -> lane holds P[q=lr][k=lg*4+r] ->
// exp+pack in regs -> PV via mfma_16x16x16 over full 256d (acco[2][16]).
// ONE barrier per kt. Epilogue merges the two k-halves via LDS.
// LDS: K dbuf 2x32K @0, V dbuf 2x32K @65536 = 128 KB (reused for merge).
// ---------------------------------------------------------------------------
__global__
__attribute__((amdgpu_flat_work_group_size(512, 512), amdgpu_waves_per_eu(2, 2)))
void k_attn(
    const unsigned short* __restrict__ Qb, const unsigned short* __restrict__ Kb,
    const unsigned short* __restrict__ Vt, float* __restrict__ out,
    float* __restrict__ part, int nkt)
{
    extern __shared__ char smem[];
    const int qt = blockIdx.x, kh = blockIdx.y, b = blockIdx.z;
    const int tid = threadIdx.x, w = tid >> 6, lane = tid & 63;
    const int lr = lane & 15, lg = lane >> 4;
    const int wqs = w & 3, wkh = w >> 2;
    const int qbase = qt * 128, q0 = wqs * 32;
    const int k0 = kh * nkt * 64;
    const int k0w = wkh * 32;            // this wave's k-offset inside the tile

    // staging lane offsets (elements) within one 64k tile, pre-swizzled
    int koff[4], voff[4];
#pragma unroll
    for (int i = 0; i < 4; ++i) {
        int L = w * 256 + i * 64 + lane;
        int r = L >> 5, c = (L & 31) ^ (r & 7);
        koff[i] = r * 256 + c * 8;
        int d = L >> 3, c2 = (L & 7) ^ (d & 7);
        voff[i] = d * 8192 + c2 * 8;
    }
    const unsigned short* kbp = Kb + (size_t)(b * N_ + k0) * 256;
    const unsigned short* vbp = Vt + (size_t)b * 256 * 8192 + k0;

    // prologue: stage tile 0 -> buffer 0
#pragma unroll
    for (int i = 0; i < 4; ++i) {
        gll16(kbp + koff[i], smem + (size_t)(w * 256 + i * 64) * 16);
        gll16(vbp + voff[i], smem + 65536 + (size_t)(w * 256 + i * 64) * 16);
    }
    kbp += 64 * 256;
    vbp += 64;

    // hoist Q as B-fragments: 32 rows (2 frags) x 8 k-slices = 64 VGPR
    short8 qfr[2][8];
#pragma unroll
    for (int qf = 0; qf < 2; ++qf) {
        const unsigned short* qrow =
            Qb + (size_t)(b * N_ + qbase + q0 + qf * 16 + lr) * 256;
#pragma unroll
        for (int ks = 0; ks < 8; ++ks) {
            qfr[qf][ks] = ldg8(qrow + ks * 32 + lg * 8);
            PIN8(qfr[qf][ks]);
        }
    }

    f32x4 acco[2][16] = {};   // [qf][df]: 32q x 256d partial (own k-half)

    for (int kt = 0; kt < nkt; ++kt) {
        const int cur = kt & 1;
        char* sK = smem + cur * 32768;
        char* sV = smem + 65536 + cur * 32768;

        WAIT_VM0();                  // own staging of tile kt landed
        BARRIER();                   // all staging landed; prev PV done
        __builtin_amdgcn_sched_barrier(0);

        if (kt + 1 < nkt) {
            char* nK = smem + (cur ^ 1) * 32768;
            char* nV = smem + 65536 + (cur ^ 1) * 32768;
#pragma unroll
            for (int i = 0; i < 4; ++i) {
                gll16(kbp + koff[i], nK + (size_t)(w * 256 + i * 64) * 16);
                gll16(vbp + voff[i], nV + (size_t)(w * 256 + i * 64) * 16);
            }
            kbp += 64 * 256;
            vbp += 64;
        }

        // ---- S phase: S^T = mfma(K, Q); 32q x 32k (own half) ----
        f32x4 sacc[2][2] = {};   // [qf][kf]
        __builtin_amdgcn_s_setprio(1);
#pragma unroll
        for (int ks = 0; ks < 8; ++ks) {
            int coff = (ks * 32 + lg * 8) * 2;
#pragma unroll
            for (int kf = 0; kf < 2; ++kf) {
                int krow = k0w + kf * 16 + lr;
                int off = (krow * 512 + coff) ^ ((krow & 7) << 4);
                short8 kbf = *reinterpret_cast<const short8*>(sK + off);
                sacc[0][kf] = mfma16(kbf, qfr[0][ks], sacc[0][kf]);
                sacc[1][kf] = mfma16(kbf, qfr[1][ks], sacc[1][kf]);
            }
        }
        __builtin_amdgcn_s_setprio(0);

        // ---- P = exp(S*SCALE), packed in-register as 16x16x16 A-frags ----
        // lane holds S[q = q0+qf*16+lr][k = k0w+kf*16+lg*4+r]
        short4_t pa[2][2];
#pragma unroll
        for (int qf = 0; qf < 2; ++qf)
#pragma unroll
            for (int kf = 0; kf < 2; ++kf) {
                short4_t v;
#pragma unroll
                for (int r = 0; r < 4; ++r)
                    v[r] = (short)f2bf(__expf(sacc[qf][kf][r] * SCALE));
                pa[qf][kf] = v;
            }

        // ---- PV phase: 32q x 256d over own 32k, K=16 MFMAs ----
        __builtin_amdgcn_s_setprio(1);
#pragma unroll
        for (int df = 0; df < 16; ++df) {
            int d = df * 16 + lr;
#pragma unroll
            for (int kf = 0; kf < 2; ++kf) {
                int kcol = (k0w + kf * 16 + lg * 4) * 2;
                int offv = (d * 128 + kcol) ^ ((d & 7) << 4);
                short4_t vb = *reinterpret_cast<const short4_t*>(sV + offv);
                acco[0][df] = mfma1616(pa[0][kf], vb, acco[0][df]);
                acco[1][df] = mfma1616(pa[1][kf], vb, acco[1][df]);
            }
        }
        __builtin_amdgcn_s_setprio(0);
    }

    // ---- epilogue: merge the two k-halves via LDS, then store ----
    __syncthreads();                       // all PV reads of smem done
    float* red = (float*)smem;             // [4 strips][32 q][256 d] f32 = 128 KB
    if (wkh == 1) {
#pragma unroll
        for (int qf = 0; qf < 2; ++qf)
#pragma unroll
            for (int df = 0; df < 16; ++df) {
                int ql = qf * 16 + lg * 4;
                int d = df * 16 + lr;
#pragma unroll
                for (int r = 0; r < 4; ++r)
                    red[(size_t)(wqs * 32 + ql + r) * 256 + d] = acco[qf][df][r];
            }
    }
    __syncthreads();
    if (wkh == 0) {
        float* dst = (kh == 0) ? out : part;
#pragma unroll
        for (int qf = 0; qf < 2; ++qf)
#pragma unroll
            for (int df = 0; df < 16; ++df) {
                int ql = qf * 16 + lg * 4;
                int d = df * 16 + lr;
#pragma unroll
                for (int r = 0; r < 4; ++r) {
                    float s = acco[qf][df][r] +
                              red[(size_t)(wqs * 32 + ql + r) * 256 + d];
                    int q = qbase + q0 + ql + r;
                    dst[(size_t)(b * N_ + q) * 256 + d] = s;
                }
            }
    }
}

// out += part  (4.2M f32)
__global__ __launch_bounds__(256) void k_add(
    float* __restrict__ out, const float* __restrict__ part)
{
    int t = blockIdx.x * 256 + threadIdx.x;
#pragma unroll
    for (int i = 0; i < 4; ++i) {
        int idx = t + i * 262144;
        float4 a = reinterpret_cast<float4*>(out)[idx];
        float4 p = reinterpret_cast<const float4*>(part)[idx];
        a.x += p.x; a.y += p.y; a.z += p.z; a.w += p.w;
        reinterpret_cast<float4*>(out)[idx] = a;
    }
}

extern "C" void kernel_launch(void* const* d_in, const int* in_sizes, int n_in,
                              void* d_out, int out_size, void* d_ws, size_t ws_size,
                              hipStream_t stream)
{
    const float* x  = (const float*)d_in[0];
    const float* Wq = (const float*)d_in[1];
    const float* Wk = (const float*)d_in[2];
    const float* Wv = (const float*)d_in[3];

    char* ws = (char*)d_ws;
    unsigned short* Qb = (unsigned short*)(ws);              //  8 MB
    unsigned short* Kb = (unsigned short*)(ws + 8388608);    //  8 MB
    unsigned short* Vt = (unsigned short*)(ws + 16777216);   //  8 MB
    float* Zpart       = (float*)(ws + 25165824);            // 256 KB
    unsigned short* Wb = (unsigned short*)(ws + 25493504);   // 384 KB
    float* part1       = (float*)(ws + 25886720);            //  16 MB
    float* out = (float*)d_out;

    k_cvtw<<<dim3(96), dim3(256), 0, stream>>>(Wq, Wk, Wv, Wb);
    k_proj<<<dim3(256), dim3(512), 0, stream>>>(x, Wb, Qb, Kb, Vt);
    k_zsum<<<dim3(2, 128, 2), dim3(512), 0, stream>>>(Qb, Kb, Zpart);
    k_scalev<<<dim3(2048), dim3(256), 0, stream>>>(Vt, Zpart);

    hipFuncSetAttribute((const void*)k_attn,
                        hipFuncAttributeMaxDynamicSharedMemorySize, 131072);
    if (ws_size >= (size_t)25886720 + 16777216) {
        k_attn<<<dim3(64, 2, 2), dim3(512), 131072, stream>>>(
            Qb, Kb, Vt, out, part1, 64);
        k_add<<<dim3(1024), dim3(256), 0, stream>>>(out, part1);
    } else {
        k_attn<<<dim3(64, 1, 2), dim3(512), 131072, stream>>>(
            Qb, Kb, Vt, out, out, 128);
    }
}

// Round 9
// 380.274 us; speedup vs baseline: 1.2284x; 1.2284x over previous
//
#include <hip/hip_runtime.h>
#include <hip/hip_bf16.h>

// Attention with softmax over the QUERY axis (axis=1):
//   attn[:,q,k] = exp(S[q,k]) / Z[k],  Z[k] = sum_q exp(S[q,k])
//   out = expS @ (diag(1/Z) V)   -- 1/Z folded into V by k_scalev.
// B=2, N=8192, D=256. All matmuls via mfma_f32_16x16x32_bf16.
// R9: k_attn reverted to the proven R2 structure (qtile 64, BK 64, no k-split,
// 220us) + PIN on hoisted Q (R6: -22us). k_zsum back to multi-block occupancy.

#define N_ 8192
#define SCALE 0.0625f

typedef __attribute__((ext_vector_type(8))) short short8;
typedef __attribute__((ext_vector_type(4))) float f32x4;
typedef __attribute__((ext_vector_type(4))) unsigned short ushort4_t;

__device__ inline unsigned short f2bf(float f) {
    unsigned int x = __float_as_uint(f);
    unsigned int r = (x + 0x7fffu + ((x >> 16) & 1u)) >> 16;  // RNE
    return (unsigned short)r;
}

__device__ inline short8 ldg8(const unsigned short* p) {
    return *reinterpret_cast<const short8*>(p);
}

__device__ inline short8 cvt8(const float* p) {
    float4 a = *(const float4*)p;
    float4 b = *(const float4*)(p + 4);
    short8 r;
    r[0] = (short)f2bf(a.x); r[1] = (short)f2bf(a.y);
    r[2] = (short)f2bf(a.z); r[3] = (short)f2bf(a.w);
    r[4] = (short)f2bf(b.x); r[5] = (short)f2bf(b.y);
    r[6] = (short)f2bf(b.z); r[7] = (short)f2bf(b.w);
    return r;
}

__device__ inline f32x4 mfma16(short8 a, short8 b, f32x4 c) {
    return __builtin_amdgcn_mfma_f32_16x16x32_bf16(a, b, c, 0, 0, 0);
}

__device__ inline float bf2f(unsigned short u) {
    return __uint_as_float(((unsigned)u) << 16);
}

#define PIN8(v) asm volatile("" : "+v"(v))

typedef __attribute__((address_space(3))) unsigned int lds_u32;
typedef __attribute__((address_space(1))) const unsigned int glb_u32;
__device__ __forceinline__ void gll16(const void* g, void* l) {
    __builtin_amdgcn_global_load_lds((glb_u32*)g, (lds_u32*)l, 16, 0, 0);
}
#define WAIT_VM0()   asm volatile("s_waitcnt vmcnt(0)" ::: "memory")
#define WAIT_LGKM0() asm volatile("s_waitcnt lgkmcnt(0)" ::: "memory")
#define BARRIER()    __builtin_amdgcn_s_barrier()

// ---------------------------------------------------------------------------
// Kernel 0: W (3 x 256x256 f32) -> Wb (768x256 bf16), concatenated Q|K|V.
// ---------------------------------------------------------------------------
__global__ __launch_bounds__(256) void k_cvtw(
    const float* __restrict__ Wq, const float* __restrict__ Wk,
    const float* __restrict__ Wv, unsigned short* __restrict__ Wb)
{
    int t = blockIdx.x * 256 + threadIdx.x;
    int e8 = t * 8;
    const float* src = (e8 < 65536) ? Wq + e8
                     : (e8 < 131072) ? Wk + (e8 - 65536)
                                     : Wv + (e8 - 131072);
    *reinterpret_cast<short8*>(Wb + e8) = cvt8(src);
}

// ---------------------------------------------------------------------------
// Kernel 1: QKV projection, x read ONCE (proven R5).
// ---------------------------------------------------------------------------
__global__ __launch_bounds__(512) void k_proj(
    const float* __restrict__ x, const unsigned short* __restrict__ Wb,
    unsigned short* __restrict__ Qb, unsigned short* __restrict__ Kb,
    unsigned short* __restrict__ Vt)
{
    __shared__ unsigned short sX[64 * 256];   // 32 KB, XOR-swizzled
    int rb = blockIdx.x;
    int tid = threadIdx.x, w = tid >> 6, lane = tid & 63;
    int lr = lane & 15, lg = lane >> 4;

#pragma unroll
    for (int i = 0; i < 4; ++i) {
        int g = tid + i * 512;
        int r = g >> 5, c = g & 31;
        int off = (r * 512 + c * 16) ^ ((r & 7) << 4);
        *reinterpret_cast<short8*>(reinterpret_cast<char*>(sX) + off) =
            cvt8(x + (size_t)(rb * 64 + r) * 256 + c * 8);
    }
    __syncthreads();

    f32x4 acc[4][6] = {};
#pragma unroll
    for (int ks = 0; ks < 8; ++ks) {
        int coff = (ks * 32 + lg * 8) * 2;
        short8 xf[4];
#pragma unroll
        for (int rf = 0; rf < 4; ++rf) {
            int row = rf * 16 + lr;
            int off = (row * 512 + coff) ^ ((row & 7) << 4);
            xf[rf] = *reinterpret_cast<const short8*>(
                reinterpret_cast<const char*>(sX) + off);
        }
#pragma unroll
        for (int cf = 0; cf < 6; ++cf) {
            int e = w * 96 + cf * 16 + lr;
            short8 bfr = ldg8(Wb + (size_t)e * 256 + ks * 32 + lg * 8);
#pragma unroll
            for (int rf = 0; rf < 4; ++rf)
                acc[rf][cf] = mfma16(xf[rf], bfr, acc[rf][cf]);
        }
    }

#pragma unroll
    for (int rf = 0; rf < 4; ++rf)
#pragma unroll
        for (int cf = 0; cf < 6; ++cf) {
            int e0c = w * 96 + cf * 16;
            int mat = e0c >> 8;               // 0:Q 1:K 2:V
            int ecol = (e0c & 255) + lr;
            int rbase = rb * 64 + rf * 16 + lg * 4;
            if (mat < 2) {
                unsigned short* dst = (mat == 0) ? Qb : Kb;
#pragma unroll
                for (int r = 0; r < 4; ++r)
                    dst[(size_t)(rbase + r) * 256 + ecol] = f2bf(acc[rf][cf][r]);
            } else {
                int bidx = rbase >> 13, nr = rbase & 8191;
                ushort4_t v;
#pragma unroll
                for (int r = 0; r < 4; ++r) v[r] = f2bf(acc[rf][cf][r]);
                *reinterpret_cast<ushort4_t*>(
                    Vt + ((size_t)bidx * 256 + ecol) * 8192 + nr) = v;
            }
        }
}

// ---------------------------------------------------------------------------
// Kernel 2: Z partials. Pinned K frags; default occupancy (33KB LDS ->
// 2 blocks/CU for latency hiding of the streamed Q loads).
// ---------------------------------------------------------------------------
__global__ __launch_bounds__(512) void k_zsum(
    const unsigned short* __restrict__ Qb, const unsigned short* __restrict__ Kb,
    float* __restrict__ Zpart)
{
    __shared__ unsigned short sK[64 * 256];
    __shared__ float zred[8][64];
    int qc = blockIdx.x, kt = blockIdx.y, b = blockIdx.z;
    int tid = threadIdx.x;

    for (int i = 0; i < 4; ++i) {
        int g = tid + i * 512;
        int r = g >> 5, c = g & 31;
        int off = (r * 512 + c * 16) ^ ((r & 7) << 4);
        *reinterpret_cast<short8*>(reinterpret_cast<char*>(sK) + off) =
            ldg8(Kb + (size_t)(b * N_ + kt * 64 + r) * 256 + c * 8);
    }
    __syncthreads();

    int w = tid >> 6, lane = tid & 63, lr = lane & 15, lg = lane >> 4;

    short8 kfr[4][8];
#pragma unroll
    for (int n = 0; n < 4; ++n)
#pragma unroll
        for (int ks = 0; ks < 8; ++ks) {
            int krow = n * 16 + lr;
            int off = (krow * 512 + (ks * 32 + lg * 8) * 2) ^ ((krow & 7) << 4);
            kfr[n][ks] = *reinterpret_cast<const short8*>(
                reinterpret_cast<const char*>(sK) + off);
            PIN8(kfr[n][ks]);
        }

    float zsum[4] = {0.f, 0.f, 0.f, 0.f};
    for (int it = 0; it < 32; ++it) {
        int qb = qc * 4096 + it * 128 + w * 16;
        const unsigned short* qrow = Qb + (size_t)(b * N_ + qb + lr) * 256;
        f32x4 acc[4] = {};
        for (int ks = 0; ks < 8; ++ks) {
            int d0 = ks * 32 + lg * 8;
            short8 a = ldg8(qrow + d0);
#pragma unroll
            for (int n = 0; n < 4; ++n)
                acc[n] = mfma16(a, kfr[n][ks], acc[n]);
        }
#pragma unroll
        for (int n = 0; n < 4; ++n)
#pragma unroll
            for (int r = 0; r < 4; ++r)
                zsum[n] += __expf(acc[n][r] * SCALE);
    }
#pragma unroll
    for (int n = 0; n < 4; ++n) {
        float v = zsum[n];
        v += __shfl_xor(v, 16);
        v += __shfl_xor(v, 32);
        if (lg == 0) zred[w][n * 16 + lr] = v;
    }
    __syncthreads();
    if (tid < 64) {
        float s = 0.f;
        for (int ww = 0; ww < 8; ++ww) s += zred[ww][tid];
        Zpart[(size_t)(qc * 2 + b) * N_ + kt * 64 + tid] = s;
    }
}

// ---------------------------------------------------------------------------
// Kernel 2.5: V' = V / Z (in place on Vt, bf16). Reads Zpart directly.
// ---------------------------------------------------------------------------
__global__ __launch_bounds__(256) void k_scalev(
    unsigned short* __restrict__ Vt, const float* __restrict__ Zpart)
{
    int t = blockIdx.x * 256 + threadIdx.x;
    int b = t >> 18, g = t & 262143;
    int d = g >> 10, k8 = (g & 1023) * 8;
    unsigned short* p = Vt + ((size_t)b * 256 + d) * 8192 + k8;
    short8 v = *reinterpret_cast<short8*>(p);
    const float* za = Zpart + (size_t)b * N_ + k8;          // qc=0
    const float* zb = Zpart + (size_t)(2 + b) * N_ + k8;    // qc=1
    float4 a0 = *(const float4*)za, a1 = *(const float4*)(za + 4);
    float4 b0 = *(const float4*)zb, b1 = *(const float4*)(zb + 4);
    float rv[8] = {1.f/(a0.x+b0.x), 1.f/(a0.y+b0.y), 1.f/(a0.z+b0.z), 1.f/(a0.w+b0.w),
                   1.f/(a1.x+b1.x), 1.f/(a1.y+b1.y), 1.f/(a1.z+b1.z), 1.f/(a1.w+b1.w)};
    short8 o;
#pragma unroll
    for (int j = 0; j < 8; ++j)
        o[j] = (short)f2bf(bf2f((unsigned short)v[j]) * rv[j]);
    *reinterpret_cast<short8*>(p) = o;
}

// ---------------------------------------------------------------------------
// Kernel 3: out[q,d] = sum_k exp(S[q,k]*SCALE) * V'[k,d].
// R2-proven structure: grid (128 qt, 2 b), 512 thr (8 waves), qtile 64,
// BK 64, full k-sweep per block (no split). Per wave: S 32q x 16k,
// PV 32q x 64d. Q hoisted + PINNED (64 VGPR). Double-buffered K/V via
// async global_load_lds (pre-swizzled source), 2 barriers per kt.
// LDS: K dbuf 2x32K @0, V dbuf 2x32K @65536, P 8K @131072 = 136 KB.
// ---------------------------------------------------------------------------
__global__ __launch_bounds__(512, 1) void k_attn(
    const unsigned short* __restrict__ Qb, const unsigned short* __restrict__ Kb,
    const unsigned short* __restrict__ Vt, float* __restrict__ out)
{
    extern __shared__ char smem[];
    const int qt = blockIdx.x, b = blockIdx.y;
    const int tid = threadIdx.x, w = tid >> 6, lane = tid & 63;
    const int lr = lane & 15, lg = lane >> 4;
    const int qbase = qt * 64;
    const int wqs = w >> 2;          // q strip: rows wqs*32 .. +32
    const int wks = w & 3;           // S k-quarter (16 k)
    const int wds = w & 3;           // PV d-quarter (64 d)
    const int q0 = wqs * 32;

    // staging sources, pre-swizzled so linear LDS dest == swizzled layout.
    const unsigned short* srcK[4];
    const unsigned short* srcV[4];
#pragma unroll
    for (int i = 0; i < 4; ++i) {
        int L = w * 256 + i * 64 + lane;
        int r = L >> 5, c = (L & 31) ^ (r & 7);
        srcK[i] = Kb + (size_t)(b * N_ + r) * 256 + c * 8;
        int d = L >> 3, c2 = (L & 7) ^ (d & 7);
        srcV[i] = Vt + ((size_t)b * 256 + d) * 8192 + c2 * 8;
    }

    // prologue: stage tile 0 into buffer 0 (async)
#pragma unroll
    for (int i = 0; i < 4; ++i) {
        gll16(srcK[i], smem + (size_t)(w * 256 + i * 64) * 16);
        gll16(srcV[i], smem + 65536 + (size_t)(w * 256 + i * 64) * 16);
        srcK[i] += 64 * 256;
        srcV[i] += 64;
    }

    // hoist Q fragments: 32 rows (2 frags) x 8 k-slices, PINNED
    short8 qfr[2][8];
#pragma unroll
    for (int qf = 0; qf < 2; ++qf) {
        const unsigned short* qrow =
            Qb + (size_t)(b * N_ + qbase + q0 + qf * 16 + lr) * 256;
#pragma unroll
        for (int ks = 0; ks < 8; ++ks) {
            qfr[qf][ks] = ldg8(qrow + ks * 32 + lg * 8);
            PIN8(qfr[qf][ks]);
        }
    }

    f32x4 acco[2][4] = {};

    for (int kt = 0; kt < 128; ++kt) {
        const int cur = kt & 1;
        char* sK = smem + cur * 32768;
        char* sV = smem + 65536 + cur * 32768;
        char* sP = smem + 131072;

        WAIT_VM0();                  // this wave's staging of tile kt done
        BARRIER();                   // all waves' slices done
        __builtin_amdgcn_sched_barrier(0);

        // issue next tile's staging into the other buffer (flies over S+PV)
        if (kt + 1 < 128) {
            char* nK = smem + (cur ^ 1) * 32768;
            char* nV = smem + 65536 + (cur ^ 1) * 32768;
#pragma unroll
            for (int i = 0; i < 4; ++i) {
                gll16(srcK[i], nK + (size_t)(w * 256 + i * 64) * 16);
                gll16(srcV[i], nV + (size_t)(w * 256 + i * 64) * 16);
                srcK[i] += 64 * 256;
                srcV[i] += 64;
            }
        }

        // ---- S phase: 32q x 16k, K from LDS, Q from regs ----
        f32x4 sacc[2] = {};
        __builtin_amdgcn_s_setprio(1);
#pragma unroll
        for (int ks = 0; ks < 8; ++ks) {
            int krow = wks * 16 + lr;
            int coff = (ks * 32 + lg * 8) * 2;
            int off = (krow * 512 + coff) ^ ((krow & 7) << 4);
            short8 kb = *reinterpret_cast<const short8*>(sK + off);
            sacc[0] = mfma16(qfr[0][ks], kb, sacc[0]);
            sacc[1] = mfma16(qfr[1][ks], kb, sacc[1]);
        }
        __builtin_amdgcn_s_setprio(0);

        // ---- P = exp(S*SCALE) -> LDS bf16 (V' already carries 1/Z) ----
#pragma unroll
        for (int qf = 0; qf < 2; ++qf)
#pragma unroll
            for (int r = 0; r < 4; ++r) {
                float p = __expf(sacc[qf][r] * SCALE);
                int q = q0 + qf * 16 + lg * 4 + r;
                int kcol = wks * 16 + lr;
                int off = (q * 128 + kcol * 2) ^ ((q & 7) << 4);
                *reinterpret_cast<unsigned short*>(sP + off) = f2bf(p);
            }

        WAIT_LGKM0();                // P writes visible
        BARRIER();
        __builtin_amdgcn_sched_barrier(0);

        // ---- PV phase: 32q x 64d over 64 k ----
        __builtin_amdgcn_s_setprio(1);
#pragma unroll
        for (int kk = 0; kk < 2; ++kk) {
            int coff = (kk * 32 + lg * 8) * 2;
            short8 pa[2];
#pragma unroll
            for (int qf = 0; qf < 2; ++qf) {
                int qq = q0 + qf * 16 + lr;
                int offa = (qq * 128 + coff) ^ ((qq & 7) << 4);
                pa[qf] = *reinterpret_cast<const short8*>(sP + offa);
            }
#pragma unroll
            for (int df = 0; df < 4; ++df) {
                int d = wds * 64 + df * 16 + lr;
                int offb = (d * 128 + coff) ^ ((d & 7) << 4);
                short8 vb = *reinterpret_cast<const short8*>(sV + offb);
                acco[0][df] = mfma16(pa[0], vb, acco[0][df]);
                acco[1][df] = mfma16(pa[1], vb, acco[1][df]);
            }
        }
        __builtin_amdgcn_s_setprio(0);
    }

    // epilogue: f32 store
#pragma unroll
    for (int qf = 0; qf < 2; ++qf)
#pragma unroll
        for (int df = 0; df < 4; ++df) {
            int d = wds * 64 + df * 16 + lr;
            int q0r = qbase + q0 + qf * 16 + lg * 4;
#pragma unroll
            for (int r = 0; r < 4; ++r)
                out[(size_t)(b * N_ + q0r + r) * 256 + d] = acco[qf][df][r];
        }
}

extern "C" void kernel_launch(void* const* d_in, const int* in_sizes, int n_in,
                              void* d_out, int out_size, void* d_ws, size_t ws_size,
                              hipStream_t stream)
{
    const float* x  = (const float*)d_in[0];
    const float* Wq = (const float*)d_in[1];
    const float* Wk = (const float*)d_in[2];
    const float* Wv = (const float*)d_in[3];

    char* ws = (char*)d_ws;
    unsigned short* Qb = (unsigned short*)(ws);              //  8 MB
    unsigned short* Kb = (unsigned short*)(ws + 8388608);    //  8 MB
    unsigned short* Vt = (unsigned short*)(ws + 16777216);   //  8 MB
    float* Zpart       = (float*)(ws + 25165824);            // 256 KB
    unsigned short* Wb = (unsigned short*)(ws + 25493504);   // 384 KB
    float* out = (float*)d_out;

    k_cvtw<<<dim3(96), dim3(256), 0, stream>>>(Wq, Wk, Wv, Wb);
    k_proj<<<dim3(256), dim3(512), 0, stream>>>(x, Wb, Qb, Kb, Vt);
    k_zsum<<<dim3(2, 128, 2), dim3(512), 0, stream>>>(Qb, Kb, Zpart);
    k_scalev<<<dim3(2048), dim3(256), 0, stream>>>(Vt, Zpart);

    hipFuncSetAttribute((const void*)k_attn,
                        hipFuncAttributeMaxDynamicSharedMemorySize, 139264);
    k_attn<<<dim3(128, 2), dim3(512), 139264, stream>>>(Qb, Kb, Vt, out);
}

// Round 10
// 303.931 us; speedup vs baseline: 1.5370x; 1.2512x over previous
//
#include <hip/hip_runtime.h>
#include <hip/hip_bf16.h>

// Attention with softmax over the QUERY axis (axis=1):
//   attn[:,q,k] = exp(S[q,k]) / Z[k],  Z[k] = sum_q exp(S[q,k])
//   out = expS @ (diag(1/Z) V)   -- 1/Z folded into V by k_zv's epilogue.
// B=2, N=8192, D=256. All matmuls via mfma_f32_16x16x32_bf16.
// R10: zsum+scalev fused into k_zv: K-tile in regs (64 VGPR/wave), Q streamed
// via global_load_lds dbuf (1 barrier/it, no P phase), epilogue scales Vt
// in place. k_attn frozen at the proven 221us R2/R9 structure.

#define N_ 8192
#define SCALE 0.0625f

typedef __attribute__((ext_vector_type(8))) short short8;
typedef __attribute__((ext_vector_type(4))) float f32x4;
typedef __attribute__((ext_vector_type(4))) unsigned short ushort4_t;

__device__ inline unsigned short f2bf(float f) {
    unsigned int x = __float_as_uint(f);
    unsigned int r = (x + 0x7fffu + ((x >> 16) & 1u)) >> 16;  // RNE
    return (unsigned short)r;
}

__device__ inline short8 ldg8(const unsigned short* p) {
    return *reinterpret_cast<const short8*>(p);
}

__device__ inline short8 cvt8(const float* p) {
    float4 a = *(const float4*)p;
    float4 b = *(const float4*)(p + 4);
    short8 r;
    r[0] = (short)f2bf(a.x); r[1] = (short)f2bf(a.y);
    r[2] = (short)f2bf(a.z); r[3] = (short)f2bf(a.w);
    r[4] = (short)f2bf(b.x); r[5] = (short)f2bf(b.y);
    r[6] = (short)f2bf(b.z); r[7] = (short)f2bf(b.w);
    return r;
}

__device__ inline f32x4 mfma16(short8 a, short8 b, f32x4 c) {
    return __builtin_amdgcn_mfma_f32_16x16x32_bf16(a, b, c, 0, 0, 0);
}

__device__ inline float bf2f(unsigned short u) {
    return __uint_as_float(((unsigned)u) << 16);
}

#define PIN8(v) asm volatile("" : "+v"(v))

typedef __attribute__((address_space(3))) unsigned int lds_u32;
typedef __attribute__((address_space(1))) const unsigned int glb_u32;
__device__ __forceinline__ void gll16(const void* g, void* l) {
    __builtin_amdgcn_global_load_lds((glb_u32*)g, (lds_u32*)l, 16, 0, 0);
}
#define WAIT_VM0()   asm volatile("s_waitcnt vmcnt(0)" ::: "memory")
#define WAIT_LGKM0() asm volatile("s_waitcnt lgkmcnt(0)" ::: "memory")
#define BARRIER()    __builtin_amdgcn_s_barrier()

// ---------------------------------------------------------------------------
// Kernel 0: W (3 x 256x256 f32) -> Wb (768x256 bf16), concatenated Q|K|V.
// ---------------------------------------------------------------------------
__global__ __launch_bounds__(256) void k_cvtw(
    const float* __restrict__ Wq, const float* __restrict__ Wk,
    const float* __restrict__ Wv, unsigned short* __restrict__ Wb)
{
    int t = blockIdx.x * 256 + threadIdx.x;
    int e8 = t * 8;
    const float* src = (e8 < 65536) ? Wq + e8
                     : (e8 < 131072) ? Wk + (e8 - 65536)
                                     : Wv + (e8 - 131072);
    *reinterpret_cast<short8*>(Wb + e8) = cvt8(src);
}

// ---------------------------------------------------------------------------
// Kernel 1: QKV projection, x read ONCE (proven R5).
// ---------------------------------------------------------------------------
__global__ __launch_bounds__(512) void k_proj(
    const float* __restrict__ x, const unsigned short* __restrict__ Wb,
    unsigned short* __restrict__ Qb, unsigned short* __restrict__ Kb,
    unsigned short* __restrict__ Vt)
{
    __shared__ unsigned short sX[64 * 256];   // 32 KB, XOR-swizzled
    int rb = blockIdx.x;
    int tid = threadIdx.x, w = tid >> 6, lane = tid & 63;
    int lr = lane & 15, lg = lane >> 4;

#pragma unroll
    for (int i = 0; i < 4; ++i) {
        int g = tid + i * 512;
        int r = g >> 5, c = g & 31;
        int off = (r * 512 + c * 16) ^ ((r & 7) << 4);
        *reinterpret_cast<short8*>(reinterpret_cast<char*>(sX) + off) =
            cvt8(x + (size_t)(rb * 64 + r) * 256 + c * 8);
    }
    __syncthreads();

    f32x4 acc[4][6] = {};
#pragma unroll
    for (int ks = 0; ks < 8; ++ks) {
        int coff = (ks * 32 + lg * 8) * 2;
        short8 xf[4];
#pragma unroll
        for (int rf = 0; rf < 4; ++rf) {
            int row = rf * 16 + lr;
            int off = (row * 512 + coff) ^ ((row & 7) << 4);
            xf[rf] = *reinterpret_cast<const short8*>(
                reinterpret_cast<const char*>(sX) + off);
        }
#pragma unroll
        for (int cf = 0; cf < 6; ++cf) {
            int e = w * 96 + cf * 16 + lr;
            short8 bfr = ldg8(Wb + (size_t)e * 256 + ks * 32 + lg * 8);
#pragma unroll
            for (int rf = 0; rf < 4; ++rf)
                acc[rf][cf] = mfma16(xf[rf], bfr, acc[rf][cf]);
        }
    }

#pragma unroll
    for (int rf = 0; rf < 4; ++rf)
#pragma unroll
        for (int cf = 0; cf < 6; ++cf) {
            int e0c = w * 96 + cf * 16;
            int mat = e0c >> 8;               // 0:Q 1:K 2:V
            int ecol = (e0c & 255) + lr;
            int rbase = rb * 64 + rf * 16 + lg * 4;
            if (mat < 2) {
                unsigned short* dst = (mat == 0) ? Qb : Kb;
#pragma unroll
                for (int r = 0; r < 4; ++r)
                    dst[(size_t)(rbase + r) * 256 + ecol] = f2bf(acc[rf][cf][r]);
            } else {
                int bidx = rbase >> 13, nr = rbase & 8191;
                ushort4_t v;
#pragma unroll
                for (int r = 0; r < 4; ++r) v[r] = f2bf(acc[rf][cf][r]);
                *reinterpret_cast<ushort4_t*>(
                    Vt + ((size_t)bidx * 256 + ecol) * 8192 + nr) = v;
            }
        }
}

// ---------------------------------------------------------------------------
// Kernel 2 (k_zv): per (kt,b): Z[k] = sum_q exp(S[q,k]*SCALE) for the 64-k
// slice, then Vt[b][:, kt*64..+64] *= 1/Z in place.
// Grid (128, 2), 512 thr (8 waves). Wave (qs=w&3, kh=w>>2): K half-tile
// (32k = kfr[2][8], 64 VGPR, pinned); per it handles q-strip qs*32..+32 of a
// 128q LDS tile. Q dbuf 2x64KB staged via global_load_lds (pre-swizzled
// source), ONE barrier per it, 64 its.
// ---------------------------------------------------------------------------
__global__ __launch_bounds__(512, 1) void k_zv(
    const unsigned short* __restrict__ Qb, const unsigned short* __restrict__ Kb,
    unsigned short* __restrict__ Vt)
{
    extern __shared__ char smem[];            // Q dbuf: 2 x 65536 B
    __shared__ float zred[8][32];
    __shared__ float zfin[64];
    const int kt = blockIdx.x, b = blockIdx.y;
    const int tid = threadIdx.x, w = tid >> 6, lane = tid & 63;
    const int lr = lane & 15, lg = lane >> 4;
    const int qs = w & 3, kh = w >> 2;

    // K half-tile in registers: rows kt*64 + kh*32 + kn*16 + lr
    short8 kfr[2][8];
#pragma unroll
    for (int kn = 0; kn < 2; ++kn)
#pragma unroll
        for (int ks = 0; ks < 8; ++ks) {
            kfr[kn][ks] = ldg8(
                Kb + (size_t)(b * N_ + kt * 64 + kh * 32 + kn * 16 + lr) * 256
                   + ks * 32 + lg * 8);
            PIN8(kfr[kn][ks]);
        }

    // staging offsets: 4096 granules of 16B per 128q tile; issue i:
    // L = i*512 + w*64 + lane (uniform base + lane*16 dest, swizzled source)
    int eoff[8], doff[8];
#pragma unroll
    for (int i = 0; i < 8; ++i) {
        int L = i * 512 + w * 64 + lane;
        int r = L >> 5, c = (L & 31) ^ (r & 7);
        eoff[i] = r * 256 + c * 8;            // element offset within q-tile
        doff[i] = L * 16;                     // byte offset in LDS buffer
    }
    const unsigned short* qbase = Qb + (size_t)b * N_ * 256;

    // prologue: stage q-tile 0 -> buffer 0
#pragma unroll
    for (int i = 0; i < 8; ++i)
        gll16(qbase + eoff[i], smem + doff[i]);

    float zs0 = 0.f, zs1 = 0.f;
    for (int it = 0; it < 64; ++it) {
        const int cur = it & 1;
        const char* sQ = smem + cur * 65536;

        WAIT_VM0();
        BARRIER();
        __builtin_amdgcn_sched_barrier(0);

        if (it + 1 < 64) {
            const unsigned short* qsrc = qbase + (size_t)(it + 1) * 128 * 256;
            char* nQ = smem + (cur ^ 1) * 65536;
#pragma unroll
            for (int i = 0; i < 8; ++i)
                gll16(qsrc + eoff[i], nQ + doff[i]);
        }

        f32x4 acc[2][2] = {};   // [qf][kn]
        __builtin_amdgcn_s_setprio(1);
#pragma unroll
        for (int ks = 0; ks < 8; ++ks) {
            int coff = (ks * 32 + lg * 8) * 2;
#pragma unroll
            for (int qf = 0; qf < 2; ++qf) {
                int row = qs * 32 + qf * 16 + lr;
                int off = (row * 512 + coff) ^ ((row & 7) << 4);
                short8 qa = *reinterpret_cast<const short8*>(sQ + off);
                acc[qf][0] = mfma16(qa, kfr[0][ks], acc[qf][0]);
                acc[qf][1] = mfma16(qa, kfr[1][ks], acc[qf][1]);
            }
        }
        __builtin_amdgcn_s_setprio(0);

        // lane holds S[q][k=kn*16+lr]; accumulate exp over q (regs r, qf)
#pragma unroll
        for (int qf = 0; qf < 2; ++qf)
#pragma unroll
            for (int r = 0; r < 4; ++r) {
                zs0 += __expf(acc[qf][0][r] * SCALE);
                zs1 += __expf(acc[qf][1][r] * SCALE);
            }
    }

    // reduce over lane groups (different q, same k)
    zs0 += __shfl_xor(zs0, 16); zs0 += __shfl_xor(zs0, 32);
    zs1 += __shfl_xor(zs1, 16); zs1 += __shfl_xor(zs1, 32);
    if (lg == 0) {
        zred[w][lr]      = zs0;   // k = kh*32 + lr
        zred[w][16 + lr] = zs1;   // k = kh*32 + 16 + lr
    }
    __syncthreads();
    if (tid < 64) {
        int kh2 = tid >> 5, kc = tid & 31;
        float z = zred[kh2 * 4 + 0][kc] + zred[kh2 * 4 + 1][kc] +
                  zred[kh2 * 4 + 2][kc] + zred[kh2 * 4 + 3][kc];
        zfin[tid] = 1.0f / z;
    }
    __syncthreads();

    // scale Vt[b][d][kt*64 .. +64] in place: 2048 granules of 8 bf16
#pragma unroll
    for (int i = 0; i < 4; ++i) {
        int G = i * 512 + tid;
        int d = G >> 3, c = G & 7;
        unsigned short* p =
            Vt + ((size_t)b * 256 + d) * 8192 + kt * 64 + c * 8;
        short8 v = *reinterpret_cast<short8*>(p);
        short8 o;
#pragma unroll
        for (int j = 0; j < 8; ++j)
            o[j] = (short)f2bf(bf2f((unsigned short)v[j]) * zfin[c * 8 + j]);
        *reinterpret_cast<short8*>(p) = o;
    }
}

// ---------------------------------------------------------------------------
// Kernel 3: out[q,d] = sum_k exp(S[q,k]*SCALE) * V'[k,d].
// Frozen R2/R9 structure (221us): grid (128 qt, 2 b), 512 thr, qtile 64,
// BK 64, K/V dbuf via global_load_lds, P via LDS, 2 barriers per kt.
// LDS: K dbuf 2x32K @0, V dbuf 2x32K @65536, P 8K @131072 = 136 KB.
// ---------------------------------------------------------------------------
__global__ __launch_bounds__(512, 1) void k_attn(
    const unsigned short* __restrict__ Qb, const unsigned short* __restrict__ Kb,
    const unsigned short* __restrict__ Vt, float* __restrict__ out)
{
    extern __shared__ char smem[];
    const int qt = blockIdx.x, b = blockIdx.y;
    const int tid = threadIdx.x, w = tid >> 6, lane = tid & 63;
    const int lr = lane & 15, lg = lane >> 4;
    const int qbase = qt * 64;
    const int wqs = w >> 2;
    const int wks = w & 3;
    const int wds = w & 3;
    const int q0 = wqs * 32;

    const unsigned short* srcK[4];
    const unsigned short* srcV[4];
#pragma unroll
    for (int i = 0; i < 4; ++i) {
        int L = w * 256 + i * 64 + lane;
        int r = L >> 5, c = (L & 31) ^ (r & 7);
        srcK[i] = Kb + (size_t)(b * N_ + r) * 256 + c * 8;
        int d = L >> 3, c2 = (L & 7) ^ (d & 7);
        srcV[i] = Vt + ((size_t)b * 256 + d) * 8192 + c2 * 8;
    }

#pragma unroll
    for (int i = 0; i < 4; ++i) {
        gll16(srcK[i], smem + (size_t)(w * 256 + i * 64) * 16);
        gll16(srcV[i], smem + 65536 + (size_t)(w * 256 + i * 64) * 16);
        srcK[i] += 64 * 256;
        srcV[i] += 64;
    }

    short8 qfr[2][8];
#pragma unroll
    for (int qf = 0; qf < 2; ++qf) {
        const unsigned short* qrow =
            Qb + (size_t)(b * N_ + qbase + q0 + qf * 16 + lr) * 256;
#pragma unroll
        for (int ks = 0; ks < 8; ++ks) {
            qfr[qf][ks] = ldg8(qrow + ks * 32 + lg * 8);
            PIN8(qfr[qf][ks]);
        }
    }

    f32x4 acco[2][4] = {};

    for (int kt = 0; kt < 128; ++kt) {
        const int cur = kt & 1;
        char* sK = smem + cur * 32768;
        char* sV = smem + 65536 + cur * 32768;
        char* sP = smem + 131072;

        WAIT_VM0();
        BARRIER();
        __builtin_amdgcn_sched_barrier(0);

        if (kt + 1 < 128) {
            char* nK = smem + (cur ^ 1) * 32768;
            char* nV = smem + 65536 + (cur ^ 1) * 32768;
#pragma unroll
            for (int i = 0; i < 4; ++i) {
                gll16(srcK[i], nK + (size_t)(w * 256 + i * 64) * 16);
                gll16(srcV[i], nV + (size_t)(w * 256 + i * 64) * 16);
                srcK[i] += 64 * 256;
                srcV[i] += 64;
            }
        }

        // ---- S phase: 32q x 16k ----
        f32x4 sacc[2] = {};
        __builtin_amdgcn_s_setprio(1);
#pragma unroll
        for (int ks = 0; ks < 8; ++ks) {
            int krow = wks * 16 + lr;
            int coff = (ks * 32 + lg * 8) * 2;
            int off = (krow * 512 + coff) ^ ((krow & 7) << 4);
            short8 kb = *reinterpret_cast<const short8*>(sK + off);
            sacc[0] = mfma16(qfr[0][ks], kb, sacc[0]);
            sacc[1] = mfma16(qfr[1][ks], kb, sacc[1]);
        }
        __builtin_amdgcn_s_setprio(0);

        // ---- P = exp(S*SCALE) -> LDS bf16 ----
#pragma unroll
        for (int qf = 0; qf < 2; ++qf)
#pragma unroll
            for (int r = 0; r < 4; ++r) {
                float p = __expf(sacc[qf][r] * SCALE);
                int q = q0 + qf * 16 + lg * 4 + r;
                int kcol = wks * 16 + lr;
                int off = (q * 128 + kcol * 2) ^ ((q & 7) << 4);
                *reinterpret_cast<unsigned short*>(sP + off) = f2bf(p);
            }

        WAIT_LGKM0();
        BARRIER();
        __builtin_amdgcn_sched_barrier(0);

        // ---- PV phase: 32q x 64d over 64 k ----
        __builtin_amdgcn_s_setprio(1);
#pragma unroll
        for (int kk = 0; kk < 2; ++kk) {
            int coff = (kk * 32 + lg * 8) * 2;
            short8 pa[2];
#pragma unroll
            for (int qf = 0; qf < 2; ++qf) {
                int qq = q0 + qf * 16 + lr;
                int offa = (qq * 128 + coff) ^ ((qq & 7) << 4);
                pa[qf] = *reinterpret_cast<const short8*>(sP + offa);
            }
#pragma unroll
            for (int df = 0; df < 4; ++df) {
                int d = wds * 64 + df * 16 + lr;
                int offb = (d * 128 + coff) ^ ((d & 7) << 4);
                short8 vb = *reinterpret_cast<const short8*>(sV + offb);
                acco[0][df] = mfma16(pa[0], vb, acco[0][df]);
                acco[1][df] = mfma16(pa[1], vb, acco[1][df]);
            }
        }
        __builtin_amdgcn_s_setprio(0);
    }

    // epilogue: f32 store
#pragma unroll
    for (int qf = 0; qf < 2; ++qf)
#pragma unroll
        for (int df = 0; df < 4; ++df) {
            int d = wds * 64 + df * 16 + lr;
            int q0r = qbase + q0 + qf * 16 + lg * 4;
#pragma unroll
            for (int r = 0; r < 4; ++r)
                out[(size_t)(b * N_ + q0r + r) * 256 + d] = acco[qf][df][r];
        }
}

extern "C" void kernel_launch(void* const* d_in, const int* in_sizes, int n_in,
                              void* d_out, int out_size, void* d_ws, size_t ws_size,
                              hipStream_t stream)
{
    const float* x  = (const float*)d_in[0];
    const float* Wq = (const float*)d_in[1];
    const float* Wk = (const float*)d_in[2];
    const float* Wv = (const float*)d_in[3];

    char* ws = (char*)d_ws;
    unsigned short* Qb = (unsigned short*)(ws);              //  8 MB
    unsigned short* Kb = (unsigned short*)(ws + 8388608);    //  8 MB
    unsigned short* Vt = (unsigned short*)(ws + 16777216);   //  8 MB
    unsigned short* Wb = (unsigned short*)(ws + 25165824);   // 384 KB
    float* out = (float*)d_out;

    k_cvtw<<<dim3(96), dim3(256), 0, stream>>>(Wq, Wk, Wv, Wb);
    k_proj<<<dim3(256), dim3(512), 0, stream>>>(x, Wb, Qb, Kb, Vt);

    hipFuncSetAttribute((const void*)k_zv,
                        hipFuncAttributeMaxDynamicSharedMemorySize, 131072);
    k_zv<<<dim3(128, 2), dim3(512), 131072, stream>>>(Qb, Kb, Vt);

    hipFuncSetAttribute((const void*)k_attn,
                        hipFuncAttributeMaxDynamicSharedMemorySize, 139264);
    k_attn<<<dim3(128, 2), dim3(512), 139264, stream>>>(Qb, Kb, Vt, out);
}